// Round 1
// baseline (1039.887 us; speedup 1.0000x reference)
//
#include <hip/hip_runtime.h>

#define N_NODES 100000
#define IN_CH 2048
#define OUT_CH 128
#define NNZ_FEAT 2000000
#define NNZ_ADJ 1600000

// ---------------- CSR build helpers ----------------

__global__ void zero_i32(int* __restrict__ p, int n) {
    int i = blockIdx.x * blockDim.x + threadIdx.x;
    if (i < n) p[i] = 0;
}

__global__ void count_rows(const int* __restrict__ rows, int nnz, int* __restrict__ cnt) {
    int i = blockIdx.x * blockDim.x + threadIdx.x;
    if (i < nnz) atomicAdd(&cnt[rows[i]], 1);
}

// exclusive scan, stage 1: per-block scan of 1024 elements
__global__ void scan1(const int* __restrict__ in, int* __restrict__ out,
                      int* __restrict__ bsums, int n) {
    __shared__ int s[1024];
    int tid = threadIdx.x;
    int i = blockIdx.x * 1024 + tid;
    int v = (i < n) ? in[i] : 0;
    s[tid] = v;
    __syncthreads();
    for (int off = 1; off < 1024; off <<= 1) {
        int t = (tid >= off) ? s[tid - off] : 0;
        __syncthreads();
        s[tid] += t;
        __syncthreads();
    }
    if (i < n) out[i] = s[tid] - v;   // exclusive
    if (tid == 1023) bsums[blockIdx.x] = s[1023];
}

// stage 2: exclusive scan of block sums (nb <= 128) in one block
__global__ void scan2(int* __restrict__ bsums, int nb) {
    __shared__ int s[128];
    int tid = threadIdx.x;
    int v = (tid < nb) ? bsums[tid] : 0;
    s[tid] = v;
    __syncthreads();
    for (int off = 1; off < 128; off <<= 1) {
        int t = (tid >= off) ? s[tid - off] : 0;
        __syncthreads();
        s[tid] += t;
        __syncthreads();
    }
    if (tid < nb) bsums[tid] = s[tid] - v;
}

// stage 3: add scanned block offsets
__global__ void scan3(int* __restrict__ out, const int* __restrict__ bsums, int n) {
    int i = blockIdx.x * 1024 + threadIdx.x;
    if (i < n) out[i] += bsums[blockIdx.x];
}

__global__ void copy_i32(const int* __restrict__ in, int* __restrict__ out, int n) {
    int i = blockIdx.x * blockDim.x + threadIdx.x;
    if (i < n) out[i] = in[i];
}

__global__ void scatter_csr(const int* __restrict__ rows, const int* __restrict__ cols,
                            const float* __restrict__ vals, int nnz,
                            int* __restrict__ cur, int* __restrict__ ccols,
                            float* __restrict__ cvals) {
    int i = blockIdx.x * blockDim.x + threadIdx.x;
    if (i < nnz) {
        int r = rows[i];
        int p = atomicAdd(&cur[r], 1);
        ccols[p] = cols[i];
        cvals[p] = vals[i];
    }
}

// ---------------- SpMM kernels ----------------

// out[r,:] = relu(bias + sum_k v_k * W[c_k, :])   (one block of 128 per row)
__global__ void spmm_weight(const int* __restrict__ rp, const int* __restrict__ cc,
                            const float* __restrict__ cv, const float* __restrict__ W,
                            const float* __restrict__ bias, float* __restrict__ out) {
    int r = blockIdx.x, t = threadIdx.x;
    int k0 = rp[r], k1 = rp[r + 1];
    float acc = bias[t];
    for (int k = k0; k < k1; ++k) {
        int c = cc[k];
        float v = cv[k];
        acc = fmaf(v, W[(long)c * OUT_CH + t], acc);
    }
    out[(long)r * OUT_CH + t] = fmaxf(acc, 0.0f);
}

// out[r,:] = sum_k v_k * hin[c_k, :]   (one block of 128 per row)
__global__ void spmm_adj(const int* __restrict__ rp, const int* __restrict__ cc,
                         const float* __restrict__ cv, const float* __restrict__ hin,
                         float* __restrict__ hout) {
    int r = blockIdx.x, t = threadIdx.x;
    int k0 = rp[r], k1 = rp[r + 1];
    float acc = 0.0f;
    for (int k = k0; k < k1; ++k) {
        int c = cc[k];
        float v = cv[k];
        acc = fmaf(v, hin[(long)c * OUT_CH + t], acc);
    }
    hout[(long)r * OUT_CH + t] = acc;
}

// ---------------- driver ----------------

extern "C" void kernel_launch(void* const* d_in, const int* in_sizes, int n_in,
                              void* d_out, int out_size, void* d_ws, size_t ws_size,
                              hipStream_t stream) {
    const int*   frows = (const int*)d_in[0];
    const int*   fcols = (const int*)d_in[1];
    const float* fvals = (const float*)d_in[2];
    const int*   arows = (const int*)d_in[3];
    const int*   acols = (const int*)d_in[4];
    const float* avals = (const float*)d_in[5];
    const float* W     = (const float*)d_in[6];
    const float* bias  = (const float*)d_in[7];
    float* out = (float*)d_out;

    const int NP1 = N_NODES + 1;

    // workspace carve-up (256B aligned)
    char* ws = (char*)d_ws;
    size_t off = 0;
    auto alloc = [&](size_t bytes) {
        size_t o = off;
        off = (off + bytes + 255) & ~(size_t)255;
        return o;
    };
    int*   frp  = (int*)  (ws + alloc((size_t)NP1 * 4));
    int*   fcc  = (int*)  (ws + alloc((size_t)NNZ_FEAT * 4));
    float* fcv  = (float*)(ws + alloc((size_t)NNZ_FEAT * 4));
    int*   arp  = (int*)  (ws + alloc((size_t)NP1 * 4));
    int*   acc_ = (int*)  (ws + alloc((size_t)NNZ_ADJ * 4));
    float* acv  = (float*)(ws + alloc((size_t)NNZ_ADJ * 4));
    int*   cur  = (int*)  (ws + alloc((size_t)NP1 * 4));
    int*   bsum = (int*)  (ws + alloc(128 * 4));
    float* hbuf = (float*)(ws + alloc((size_t)N_NODES * OUT_CH * 4));
    (void)ws_size; (void)off; (void)in_sizes; (void)n_in; (void)out_size;

    const int nscan = (NP1 + 1023) / 1024;  // 98

    // ---- build feat CSR ----
    zero_i32<<<(NP1 + 255) / 256, 256, 0, stream>>>(cur, NP1);
    count_rows<<<(NNZ_FEAT + 255) / 256, 256, 0, stream>>>(frows, NNZ_FEAT, cur);
    scan1<<<nscan, 1024, 0, stream>>>(cur, frp, bsum, NP1);
    scan2<<<1, 128, 0, stream>>>(bsum, nscan);
    scan3<<<nscan, 1024, 0, stream>>>(frp, bsum, NP1);
    copy_i32<<<(N_NODES + 255) / 256, 256, 0, stream>>>(frp, cur, N_NODES);
    scatter_csr<<<(NNZ_FEAT + 255) / 256, 256, 0, stream>>>(frows, fcols, fvals, NNZ_FEAT,
                                                            cur, fcc, fcv);

    // ---- build adj CSR ----
    zero_i32<<<(NP1 + 255) / 256, 256, 0, stream>>>(cur, NP1);
    count_rows<<<(NNZ_ADJ + 255) / 256, 256, 0, stream>>>(arows, NNZ_ADJ, cur);
    scan1<<<nscan, 1024, 0, stream>>>(cur, arp, bsum, NP1);
    scan2<<<1, 128, 0, stream>>>(bsum, nscan);
    scan3<<<nscan, 1024, 0, stream>>>(arp, bsum, NP1);
    copy_i32<<<(N_NODES + 255) / 256, 256, 0, stream>>>(arp, cur, N_NODES);
    scatter_csr<<<(NNZ_ADJ + 255) / 256, 256, 0, stream>>>(arows, acols, avals, NNZ_ADJ,
                                                           cur, acc_, acv);

    // ---- h0 = relu(F*W + b) ----
    spmm_weight<<<N_NODES, 128, 0, stream>>>(frp, fcc, fcv, W, bias, hbuf);

    // ---- h = A*h, three times (ends in d_out) ----
    spmm_adj<<<N_NODES, 128, 0, stream>>>(arp, acc_, acv, hbuf, out);
    spmm_adj<<<N_NODES, 128, 0, stream>>>(arp, acc_, acv, out, hbuf);
    spmm_adj<<<N_NODES, 128, 0, stream>>>(arp, acc_, acv, hbuf, out);
}